// Round 1
// baseline (179.163 us; speedup 1.0000x reference)
//
#include <hip/hip_runtime.h>
#include <hip/hip_bf16.h>
#include <stdint.h>

// deform_conv2d: N=8, C=256, H=W=64, OC=256, 3x3, stride=1, pad=1 -> OH=OW=64
// Strategy: im2col-fused MFMA GEMM.
//   M = 32768 (n,oh,ow), Ndim = 256 (oc), Kdim = 2304 ordered k-major (kd = k*256 + c)
//   prep1: x NCHW fp32 -> NHWC bf16 in ws (coalesced bilinear gathers over c)
//   prep2: weight (OC,C,3,3) fp32 -> bf16 chunk-major w3[t][oc][kk] (straight B staging)
//   main: 512 blocks = (n, oh); block tile 64 rows x 256 oc; 4 waves of 64x64;
//         36 chunks of 64 kdim (fixed tap k, 64 channels each).

typedef short short8 __attribute__((ext_vector_type(8)));
typedef float f32x4 __attribute__((ext_vector_type(4)));

__device__ __forceinline__ float bflo(uint32_t u) { return __uint_as_float(u << 16); }
__device__ __forceinline__ float bfhi(uint32_t u) { return __uint_as_float(u & 0xffff0000u); }
__device__ __forceinline__ uint32_t packbf(float a, float b) {
  unsigned short ua = __builtin_bit_cast(unsigned short, __float2bfloat16(a));
  unsigned short ub = __builtin_bit_cast(unsigned short, __float2bfloat16(b));
  return (uint32_t)ua | ((uint32_t)ub << 16);
}

// ---- prep 1: x NCHW fp32 -> NHWC bf16 (LDS transpose, 64x64 tiles) ----
__global__ __launch_bounds__(256) void prep_x_kernel(const float* __restrict__ x,
                                                     unsigned short* __restrict__ xb) {
  __shared__ float tile[64][65];
  int bn   = blockIdx.x >> 8;        // 8 n
  int rem  = blockIdx.x & 255;       // 64 y * 4 cblk
  int y    = rem >> 2;
  int cblk = rem & 3;
  int tid  = threadIdx.x;
  {
    int xcol = tid & 63;
    int cl0  = tid >> 6;
#pragma unroll
    for (int i = 0; i < 16; ++i) {
      int cl = cl0 + i * 4;
      tile[cl][xcol] = x[((bn * 256 + cblk * 64 + cl) * 64 + y) * 64 + xcol];
    }
  }
  __syncthreads();
  {
    int cl  = tid & 63;
    int xc0 = tid >> 6;
#pragma unroll
    for (int i = 0; i < 16; ++i) {
      int xc = xc0 + i * 4;
      xb[((bn * 64 + y) * 64 + xc) * 256 + cblk * 64 + cl] =
          __builtin_bit_cast(unsigned short, __float2bfloat16(tile[cl][xc]));
    }
  }
}

// ---- prep 2: weight -> bf16, layout w3[(t*256 + oc)*64 + kk], kd = k*256+c ----
__global__ __launch_bounds__(256) void prep_w_kernel(const float* __restrict__ w,
                                                     unsigned short* __restrict__ w3) {
  int idx = blockIdx.x * 256 + threadIdx.x;   // < 36*256*64 = 589824
  int t   = idx >> 14;                        // chunk (36)
  int r2  = idx & 16383;
  int oc  = r2 >> 6;
  int kk  = r2 & 63;
  int c   = (t & 3) * 64 + kk;
  int k   = t >> 2;
  w3[idx] = __builtin_bit_cast(unsigned short, __float2bfloat16(w[(oc * 256 + c) * 9 + k]));
}

// ---- main fused kernel ----
__global__ __launch_bounds__(256, 2) void deform_mfma_kernel(
    const unsigned short* __restrict__ xb,    // NHWC bf16
    const float* __restrict__ offset,         // (8, 18, 64, 64) fp32
    const unsigned short* __restrict__ w3,    // chunk-major bf16
    float* __restrict__ out) {                // (8, 256, 64, 64) fp32
  __shared__ __align__(16) unsigned short At[64 * 72];     // [row][kk] pad 72
  __shared__ __align__(16) unsigned short Btile[256 * 72]; // [oc][kk] pad 72
  __shared__ float4 cw[576];                               // bilinear wgts (valid folded in)
  __shared__ int4   cp[576];                               // clamped plane offsets y*64+x

  int bn  = blockIdx.x >> 6;
  int oh  = blockIdx.x & 63;
  int tid = threadIdx.x;

  // ---- per-block coordinate precompute: 64 ow x 9 taps ----
  for (int e = tid; e < 576; e += 256) {
    int r  = e & 63;          // ow
    int k  = e >> 6;          // tap 0..8
    int ky = k / 3 - 1;
    int kx = k % 3 - 1;
    float offy = offset[((bn * 18 + 2 * k    ) * 64 + oh) * 64 + r];
    float offx = offset[((bn * 18 + 2 * k + 1) * 64 + oh) * 64 + r];
    float y = (float)(oh + ky) + offy;
    float x = (float)(r + kx) + offx;
    float y0f = floorf(y), x0f = floorf(x);
    float fy = y - y0f, fx = x - x0f;
    int y0 = (int)y0f, x0 = (int)x0f;
    int y1 = y0 + 1, x1 = x0 + 1;
    float vy0 = (y0 >= 0 && y0 <= 63) ? 1.0f : 0.0f;
    float vy1 = (y1 >= 0 && y1 <= 63) ? 1.0f : 0.0f;
    float vx0 = (x0 >= 0 && x0 <= 63) ? 1.0f : 0.0f;
    float vx1 = (x1 >= 0 && x1 <= 63) ? 1.0f : 0.0f;
    float wy0 = (1.0f - fy) * vy0, wy1 = fy * vy1;
    float wx0 = (1.0f - fx) * vx0, wx1 = fx * vx1;
    cw[e] = make_float4(wy0 * wx0, wy0 * wx1, wy1 * wx0, wy1 * wx1);
    int y0c = min(max(y0, 0), 63), y1c = min(max(y1, 0), 63);
    int x0c = min(max(x0, 0), 63), x1c = min(max(x1, 0), 63);
    cp[e] = make_int4(y0c * 64 + x0c, y0c * 64 + x1c, y1c * 64 + x0c, y1c * 64 + x1c);
  }

  int wave  = tid >> 6;
  int lane  = tid & 63;
  int half  = lane >> 5;           // half-wave handles one row
  int cpair = (lane & 31) * 2;     // 2 channels per lane
  int mrow  = lane & 15;
  int quad  = lane >> 4;

  f32x4 acc[4][4] = {};

  const unsigned short* xbn = xb + (size_t)bn * (64 * 64 * 256);

  for (int t = 0; t < 36; ++t) {
    int k     = t >> 2;
    int cbase = (t & 3) * 64;
    __syncthreads();   // previous MFMA reads done before restage (also covers coord init at t=0)

    // ---- stage A: bilinear-sample 64 rows x 64 channels into At ----
    {
      const unsigned short* gbase = xbn + cbase + cpair;
#pragma unroll
      for (int j = 0; j < 8; ++j) {
        int r = wave * 16 + j * 2 + half;
        int e = k * 64 + r;
        float4 wv = cw[e];
        int4   pv = cp[e];
        uint32_t u00 = *(const uint32_t*)(gbase + pv.x * 256);
        uint32_t u01 = *(const uint32_t*)(gbase + pv.y * 256);
        uint32_t u10 = *(const uint32_t*)(gbase + pv.z * 256);
        uint32_t u11 = *(const uint32_t*)(gbase + pv.w * 256);
        float a0 = bflo(u00) * wv.x + bflo(u01) * wv.y + bflo(u10) * wv.z + bflo(u11) * wv.w;
        float a1 = bfhi(u00) * wv.x + bfhi(u01) * wv.y + bfhi(u10) * wv.z + bfhi(u11) * wv.w;
        *(uint32_t*)(&At[r * 72 + cpair]) = packbf(a0, a1);
      }
    }
    // ---- stage B: straight copy of 64x256 bf16 chunk ----
    {
      const unsigned short* wsrc = w3 + t * 16384;
#pragma unroll
      for (int j = 0; j < 8; ++j) {
        int g  = tid + 256 * j;      // 16B-group index: 2048 per chunk
        int oc = g >> 3;
        int kk = (g & 7) * 8;
        short8 v = *(const short8*)(wsrc + g * 8);
        *(short8*)(&Btile[oc * 72 + kk]) = v;
      }
    }
    __syncthreads();

    // ---- MFMA: 2 k-steps x (4m x 4n) ----
#pragma unroll
    for (int ks = 0; ks < 2; ++ks) {
      int ko = ks * 32 + quad * 8;
      short8 af[4], bfr[4];
#pragma unroll
      for (int m = 0; m < 4; ++m)
        af[m] = *(const short8*)(&At[(m * 16 + mrow) * 72 + ko]);
#pragma unroll
      for (int nn = 0; nn < 4; ++nn)
        bfr[nn] = *(const short8*)(&Btile[(wave * 64 + nn * 16 + mrow) * 72 + ko]);
#pragma unroll
      for (int m = 0; m < 4; ++m)
#pragma unroll
        for (int nn = 0; nn < 4; ++nn)
          acc[m][nn] = __builtin_amdgcn_mfma_f32_16x16x32_bf16(af[m], bfr[nn], acc[m][nn], 0, 0, 0);
    }
  }

  // ---- epilogue: C/D layout col=lane&15(oc), row=quad*4+reg(ow) -> float4 stores ----
  float* outp = out + (size_t)(bn * 256) * 4096 + oh * 64;
#pragma unroll
  for (int m = 0; m < 4; ++m) {
    int ow0 = m * 16 + quad * 4;
#pragma unroll
    for (int nn = 0; nn < 4; ++nn) {
      int oc = wave * 64 + nn * 16 + mrow;
      *(f32x4*)(outp + oc * 4096 + ow0) = acc[m][nn];
    }
  }
}

extern "C" void kernel_launch(void* const* d_in, const int* in_sizes, int n_in,
                              void* d_out, int out_size, void* d_ws, size_t ws_size,
                              hipStream_t stream) {
  (void)in_sizes; (void)n_in; (void)out_size; (void)ws_size;
  const float* x      = (const float*)d_in[0];
  const float* offset = (const float*)d_in[1];
  const float* weight = (const float*)d_in[2];
  float* out = (float*)d_out;

  unsigned short* xb = (unsigned short*)d_ws;                               // 16.78 MB
  unsigned short* w3 = (unsigned short*)((char*)d_ws + (size_t)8*64*64*256*2); // +1.18 MB

  prep_x_kernel<<<2048, 256, 0, stream>>>(x, xb);
  prep_w_kernel<<<2304, 256, 0, stream>>>(weight, w3);
  deform_mfma_kernel<<<512, 256, 0, stream>>>(xb, offset, w3, out);
}